// Round 1
// baseline (7200.678 us; speedup 1.0000x reference)
//
#include <hip/hip_runtime.h>
#include <math.h>

#define BN_EPS 1e-5f

// ---------------- degree count + inverse ----------------
__global__ void count_edges_k(const int* __restrict__ dst, int E, int* __restrict__ cnt) {
    int i = blockIdx.x * blockDim.x + threadIdx.x;
    int stride = gridDim.x * blockDim.x;
    for (int e = i; e < E; e += stride) atomicAdd(&cnt[dst[e]], 1);
}

__global__ void make_inv_k(const int* __restrict__ cnt, float* __restrict__ inv, int N) {
    int i = blockIdx.x * blockDim.x + threadIdx.x;
    int stride = gridDim.x * blockDim.x;
    for (int n = i; n < N; n += stride) inv[n] = 1.0f / fmaxf((float)cnt[n], 1.0f);
}

// ---------------- scatter-add aggregation (float atomics) ----------------
template<int C>
__global__ void scatter_add_k(const float* __restrict__ feat, const int* __restrict__ src,
                              const int* __restrict__ dst, int E, float* __restrict__ agg) {
    constexpr int J = C / 4;   // float4 chunks per row
    long long tid = (long long)blockIdx.x * blockDim.x + threadIdx.x;
    long long total = (long long)E * J;
    long long stride = (long long)gridDim.x * blockDim.x;
    for (long long i = tid; i < total; i += stride) {
        int e = (int)(i / J);
        int j = (int)(i % J);
        int s = src[e];
        int d = dst[e];
        float4 v = ((const float4*)(feat + (size_t)s * C))[j];
        float* p = agg + (size_t)d * C + j * 4;
        atomicAdd(p + 0, v.x);
        atomicAdd(p + 1, v.y);
        atomicAdd(p + 2, v.z);
        atomicAdd(p + 3, v.w);
    }
}

// ---------------- fused SAGE gemm: out = (inv*agg)@Wl + xin@Wr + bl ----------------
// out may alias xin (rows are staged through LDS before any store).
template<int K>
__launch_bounds__(256)
__global__ void sage_gemm_k(const float* __restrict__ aggsum, const float* __restrict__ inv,
                            const float* xin, const float* __restrict__ Wl,
                            const float* __restrict__ Wr, const float* __restrict__ bl,
                            float* out, int N) {
    constexpr int ROWS = 32;
    __shared__ float sA[ROWS][K];
    __shared__ float sX[ROWS][K];
    const int t = threadIdx.x;
    const int rowbase = blockIdx.x * ROWS;

    constexpr int J = K / 4;            // float4 per row
    constexpr int ELEMS4 = ROWS * J;
    const float4* a4 = (const float4*)(aggsum + (size_t)rowbase * K);
    const float4* x4 = (const float4*)(xin + (size_t)rowbase * K);
    float4* sA4 = (float4*)sA;
    float4* sX4 = (float4*)sX;
    for (int i = t; i < ELEMS4; i += 256) {
        int r = i / J;
        int row = rowbase + r;
        if (row < N) {
            float s = inv[row];
            float4 v = a4[i];
            v.x *= s; v.y *= s; v.z *= s; v.w *= s;
            sA4[i] = v;
            sX4[i] = x4[i];
        }
    }
    __syncthreads();

    const int col = t & 127;
    const int rh = t >> 7;              // 0 or 1
    const int rb = rh * (ROWS / 2);     // 16 rows per thread
    float acc[ROWS / 2];
    const float b = bl[col];
#pragma unroll
    for (int r = 0; r < ROWS / 2; ++r) acc[r] = b;

    for (int k4 = 0; k4 < K; k4 += 4) {
        float wl0 = Wl[(k4 + 0) * 128 + col];
        float wl1 = Wl[(k4 + 1) * 128 + col];
        float wl2 = Wl[(k4 + 2) * 128 + col];
        float wl3 = Wl[(k4 + 3) * 128 + col];
        float wr0 = Wr[(k4 + 0) * 128 + col];
        float wr1 = Wr[(k4 + 1) * 128 + col];
        float wr2 = Wr[(k4 + 2) * 128 + col];
        float wr3 = Wr[(k4 + 3) * 128 + col];
#pragma unroll
        for (int r = 0; r < ROWS / 2; ++r) {
            float4 a = *(const float4*)&sA[rb + r][k4];
            float4 x = *(const float4*)&sX[rb + r][k4];
            acc[r] += a.x * wl0 + a.y * wl1 + a.z * wl2 + a.w * wl3
                    + x.x * wr0 + x.y * wr1 + x.z * wr2 + x.w * wr3;
        }
    }

#pragma unroll
    for (int r = 0; r < ROWS / 2; ++r) {
        int row = rowbase + rb + r;
        if (row < N) out[(size_t)row * 128 + col] = acc[r];
    }
}

// ---------------- BN stats: stats[0..127]=sum, [128..255]=sumsq ----------------
__global__ void bn_stats_k(const float* __restrict__ h, int N, float* __restrict__ stats) {
    const int col = threadIdx.x & 127;
    const int part = threadIdx.x >> 7;   // 0/1
    float s = 0.f, s2 = 0.f;
    for (int r = blockIdx.x * 2 + part; r < N; r += gridDim.x * 2) {
        float v = h[(size_t)r * 128 + col];
        s += v;
        s2 += v * v;
    }
    __shared__ float red[2][256];
    red[0][threadIdx.x] = s;
    red[1][threadIdx.x] = s2;
    __syncthreads();
    if (threadIdx.x < 128) {
        atomicAdd(&stats[col], red[0][threadIdx.x] + red[0][threadIdx.x + 128]);
        atomicAdd(&stats[128 + col], red[1][threadIdx.x] + red[1][threadIdx.x + 128]);
    }
}

// stats[256..383]=scale, stats[384..511]=shift
__global__ void bn_finalize_k(const float* __restrict__ g, const float* __restrict__ be,
                              float* __restrict__ stats, int N) {
    int c = threadIdx.x;
    if (c < 128) {
        float mu = stats[c] / (float)N;
        float var = stats[128 + c] / (float)N - mu * mu;
        float sc = g[c] * rsqrtf(var + BN_EPS);
        stats[256 + c] = sc;
        stats[384 + c] = be[c] - mu * sc;
    }
}

__global__ void bn_apply_k(float* __restrict__ h, const float* __restrict__ stats, long long total4) {
    long long i = (long long)blockIdx.x * blockDim.x + threadIdx.x;
    long long stride = (long long)gridDim.x * blockDim.x;
    const float* sc = stats + 256;
    const float* sh = stats + 384;
    for (; i < total4; i += stride) {
        int c0 = (int)(i & 31) * 4;
        float4 v = ((float4*)h)[i];
        v.x = fmaxf(v.x * sc[c0 + 0] + sh[c0 + 0], 0.f);
        v.y = fmaxf(v.y * sc[c0 + 1] + sh[c0 + 1], 0.f);
        v.z = fmaxf(v.z * sc[c0 + 2] + sh[c0 + 2], 0.f);
        v.w = fmaxf(v.w * sc[c0 + 3] + sh[c0 + 3], 0.f);
        ((float4*)h)[i] = v;
    }
}

// ---------------- layer 2: out = sigmoid(((inv*agg)@Wl2 + h1@Wr2 + bl2)*wF + bF) ----------------
__global__ void layer2_k(const float* __restrict__ agg, const float* __restrict__ inv,
                         const float* __restrict__ h1, const float* __restrict__ Wl2,
                         const float* __restrict__ bl2, const float* __restrict__ Wr2,
                         const float* __restrict__ wF, const float* __restrict__ bF,
                         float* __restrict__ out, int N) {
    const int lane = threadIdx.x & 63;
    const int wid = (blockIdx.x * blockDim.x + threadIdx.x) >> 6;
    const int wstride = (gridDim.x * blockDim.x) >> 6;
    float2 wl = ((const float2*)Wl2)[lane];
    float2 wr = ((const float2*)Wr2)[lane];
    const float c_bl2 = bl2[0];
    const float c_wF = wF[0];
    const float c_bF = bF[0];
    for (int n = wid; n < N; n += wstride) {
        float2 a = ((const float2*)(agg + (size_t)n * 128))[lane];
        float2 h = ((const float2*)(h1 + (size_t)n * 128))[lane];
        float iv = inv[n];
        float s = iv * (a.x * wl.x + a.y * wl.y) + h.x * wr.x + h.y * wr.y;
#pragma unroll
        for (int off = 32; off; off >>= 1) s += __shfl_down(s, off);
        if (lane == 0) {
            float z = (s + c_bl2) * c_wF + c_bF;
            out[n] = 1.f / (1.f + expf(-z));
        }
    }
}

extern "C" void kernel_launch(void* const* d_in, const int* in_sizes, int n_in,
                              void* d_out, int out_size, void* d_ws, size_t ws_size,
                              hipStream_t stream) {
    const float* x   = (const float*)d_in[0];
    const int*   ei  = (const int*)d_in[1];
    const int E = in_sizes[1] / 2;
    const int N = in_sizes[0] / 64;
    const int* src = ei;
    const int* dst = ei + E;
    const float* Wl0 = (const float*)d_in[2];
    const float* bl0 = (const float*)d_in[3];
    const float* Wr0 = (const float*)d_in[4];
    const float* Wl1 = (const float*)d_in[5];
    const float* bl1 = (const float*)d_in[6];
    const float* Wr1 = (const float*)d_in[7];
    const float* Wl2 = (const float*)d_in[8];
    const float* bl2 = (const float*)d_in[9];
    const float* Wr2 = (const float*)d_in[10];
    const float* g0  = (const float*)d_in[11];
    const float* be0 = (const float*)d_in[12];
    const float* g1  = (const float*)d_in[13];
    const float* be1 = (const float*)d_in[14];
    const float* wF  = (const float*)d_in[15];
    const float* bF  = (const float*)d_in[16];

    float* A    = (float*)d_ws;                 // agg sums  [N,128]
    float* B    = A + (size_t)N * 128;          // h buffer  [N,128] (in-place reuse)
    int*   cnt  = (int*)(B + (size_t)N * 128);  // [N]
    float* inv  = (float*)(cnt + N);            // [N]
    float* stats = inv + N;                     // [512]
    float* out = (float*)d_out;

    const int gemm_grid = (N + 31) / 32;

    // degree counts (recomputed every call: ws is not persistent)
    hipMemsetAsync(cnt, 0, (size_t)N * sizeof(int), stream);
    count_edges_k<<<2048, 256, 0, stream>>>(dst, E, cnt);
    make_inv_k<<<512, 256, 0, stream>>>(cnt, inv, N);

    // ---- layer 0: x[N,64] -> B[N,128]
    hipMemsetAsync(A, 0, (size_t)N * 64 * sizeof(float), stream);
    scatter_add_k<64><<<4096, 256, 0, stream>>>(x, src, dst, E, A);
    sage_gemm_k<64><<<gemm_grid, 256, 0, stream>>>(A, inv, x, Wl0, Wr0, bl0, B, N);
    hipMemsetAsync(stats, 0, 256 * sizeof(float), stream);
    bn_stats_k<<<512, 256, 0, stream>>>(B, N, stats);
    bn_finalize_k<<<1, 128, 0, stream>>>(g0, be0, stats, N);
    bn_apply_k<<<2048, 256, 0, stream>>>(B, stats, (long long)N * 32);

    // ---- layer 1: B[N,128] -> B[N,128] (in place)
    hipMemsetAsync(A, 0, (size_t)N * 128 * sizeof(float), stream);
    scatter_add_k<128><<<4096, 256, 0, stream>>>(B, src, dst, E, A);
    sage_gemm_k<128><<<gemm_grid, 256, 0, stream>>>(A, inv, B, Wl1, Wr1, bl1, B, N);
    hipMemsetAsync(stats, 0, 256 * sizeof(float), stream);
    bn_stats_k<<<512, 256, 0, stream>>>(B, N, stats);
    bn_finalize_k<<<1, 128, 0, stream>>>(g1, be1, stats, N);
    bn_apply_k<<<2048, 256, 0, stream>>>(B, stats, (long long)N * 32);

    // ---- layer 2: B[N,128] -> out[N,1] (+ final linear + sigmoid)
    hipMemsetAsync(A, 0, (size_t)N * 128 * sizeof(float), stream);
    scatter_add_k<128><<<4096, 256, 0, stream>>>(B, src, dst, E, A);
    layer2_k<<<1024, 256, 0, stream>>>(A, inv, B, Wl2, bl2, Wr2, wF, bF, out, N);
}

// Round 2
// 1000.207 us; speedup vs baseline: 7.1992x; 7.1992x over previous
//
#include <hip/hip_runtime.h>
#include <math.h>

#define BN_EPS 1e-5f

// ---------------- degree count ----------------
__global__ void count_edges_k(const int* __restrict__ dst, int E, int* __restrict__ cnt) {
    int i = blockIdx.x * blockDim.x + threadIdx.x;
    int stride = gridDim.x * blockDim.x;
    for (int e = i; e < E; e += stride) atomicAdd(&cnt[dst[e]], 1);
}

// ---------------- single-block scan: off/cursor = exclusive scan(cnt), inv = 1/max(cnt,1) ----------------
__global__ void scan_k(const int* __restrict__ cnt, int* __restrict__ off,
                       int* __restrict__ cursor, float* __restrict__ inv, int N) {
    __shared__ int buf[1024];
    __shared__ int carry_s;
    const int t = threadIdx.x;
    if (t == 0) carry_s = 0;
    __syncthreads();
    for (int base = 0; base < N; base += 1024) {
        int i = base + t;
        int v = (i < N) ? cnt[i] : 0;
        buf[t] = v;
        __syncthreads();
        for (int d = 1; d < 1024; d <<= 1) {
            int add = (t >= d) ? buf[t - d] : 0;
            __syncthreads();
            buf[t] += add;
            __syncthreads();
        }
        int incl = buf[t];
        int excl = incl - v + carry_s;
        if (i < N) {
            off[i] = excl;
            cursor[i] = excl;
            inv[i] = 1.0f / fmaxf((float)v, 1.0f);
        }
        __syncthreads();
        if (t == 1023) carry_s += incl;
        __syncthreads();
    }
}

// ---------------- CSR fill (cursor ends at row end) ----------------
__global__ void csr_fill_k(const int* __restrict__ src, const int* __restrict__ dst, int E,
                           int* __restrict__ cursor, int* __restrict__ csr) {
    int i = blockIdx.x * blockDim.x + threadIdx.x;
    int stride = gridDim.x * blockDim.x;
    for (int e = i; e < E; e += stride) {
        int d = dst[e];
        int pos = atomicAdd(&cursor[d], 1);
        csr[pos] = src[e];
    }
}

// ---------------- gather-mean aggregation: agg[n] = inv[n] * sum_{e in row n} feat[csr[e]] ----------------
template<int C>
__global__ void gather_agg_k(const float* __restrict__ feat, const int* __restrict__ csr,
                             const int* __restrict__ off, const int* __restrict__ endp,
                             const float* __restrict__ inv, float* __restrict__ agg, int N) {
    const int lane = threadIdx.x & 63;
    const int n = (int)((blockIdx.x * (long long)blockDim.x + threadIdx.x) >> 6);
    if (n >= N) return;
    const int o = off[n];
    const int e_end = endp[n];
    float acc0 = 0.f, acc1 = 0.f;
    int e = o;
    if constexpr (C == 128) {
        for (; e + 1 < e_end; e += 2) {
            int s0 = csr[e], s1 = csr[e + 1];
            float2 v0 = ((const float2*)(feat + (size_t)s0 * 128))[lane];
            float2 v1 = ((const float2*)(feat + (size_t)s1 * 128))[lane];
            acc0 += v0.x + v1.x;
            acc1 += v0.y + v1.y;
        }
        if (e < e_end) {
            float2 v = ((const float2*)(feat + (size_t)csr[e] * 128))[lane];
            acc0 += v.x; acc1 += v.y;
        }
        float iv = inv[n];
        float2 r; r.x = acc0 * iv; r.y = acc1 * iv;
        ((float2*)(agg + (size_t)n * 128))[lane] = r;
    } else {
        for (; e + 1 < e_end; e += 2) {
            int s0 = csr[e], s1 = csr[e + 1];
            acc0 += feat[(size_t)s0 * C + lane];
            acc1 += feat[(size_t)s1 * C + lane];
        }
        if (e < e_end) acc0 += feat[(size_t)csr[e] * C + lane];
        agg[(size_t)n * C + lane] = (acc0 + acc1) * inv[n];
    }
}

// ---------------- fused SAGE gemm: out = agg@Wl + xin@Wr + bl (agg pre-scaled) ----------------
// out may alias xin (rows are staged through LDS before any store).
template<int K>
__launch_bounds__(256)
__global__ void sage_gemm_k(const float* __restrict__ agg, const float* xin,
                            const float* __restrict__ Wl, const float* __restrict__ Wr,
                            const float* __restrict__ bl, float* out, int N) {
    constexpr int ROWS = 32;
    __shared__ float sA[ROWS][K];
    __shared__ float sX[ROWS][K];
    const int t = threadIdx.x;
    const int rowbase = blockIdx.x * ROWS;

    constexpr int J = K / 4;
    constexpr int ELEMS4 = ROWS * J;
    const float4* a4 = (const float4*)(agg + (size_t)rowbase * K);
    const float4* x4 = (const float4*)(xin + (size_t)rowbase * K);
    float4* sA4 = (float4*)sA;
    float4* sX4 = (float4*)sX;
    for (int i = t; i < ELEMS4; i += 256) {
        int r = i / J;
        if (rowbase + r < N) {
            sA4[i] = a4[i];
            sX4[i] = x4[i];
        }
    }
    __syncthreads();

    const int col = t & 127;
    const int rh = t >> 7;
    const int rb = rh * (ROWS / 2);
    float acc[ROWS / 2];
    const float b = bl[col];
#pragma unroll
    for (int r = 0; r < ROWS / 2; ++r) acc[r] = b;

    for (int k4 = 0; k4 < K; k4 += 4) {
        float wl0 = Wl[(k4 + 0) * 128 + col];
        float wl1 = Wl[(k4 + 1) * 128 + col];
        float wl2 = Wl[(k4 + 2) * 128 + col];
        float wl3 = Wl[(k4 + 3) * 128 + col];
        float wr0 = Wr[(k4 + 0) * 128 + col];
        float wr1 = Wr[(k4 + 1) * 128 + col];
        float wr2 = Wr[(k4 + 2) * 128 + col];
        float wr3 = Wr[(k4 + 3) * 128 + col];
#pragma unroll
        for (int r = 0; r < ROWS / 2; ++r) {
            float4 a = *(const float4*)&sA[rb + r][k4];
            float4 x = *(const float4*)&sX[rb + r][k4];
            acc[r] += a.x * wl0 + a.y * wl1 + a.z * wl2 + a.w * wl3
                    + x.x * wr0 + x.y * wr1 + x.z * wr2 + x.w * wr3;
        }
    }

#pragma unroll
    for (int r = 0; r < ROWS / 2; ++r) {
        int row = rowbase + rb + r;
        if (row < N) out[(size_t)row * 128 + col] = acc[r];
    }
}

// ---------------- BN stats: stats[0..127]=sum, [128..255]=sumsq ----------------
__global__ void bn_stats_k(const float* __restrict__ h, int N, float* __restrict__ stats) {
    const int col = threadIdx.x & 127;
    const int part = threadIdx.x >> 7;
    float s = 0.f, s2 = 0.f;
    for (int r = blockIdx.x * 2 + part; r < N; r += gridDim.x * 2) {
        float v = h[(size_t)r * 128 + col];
        s += v;
        s2 += v * v;
    }
    __shared__ float red[2][256];
    red[0][threadIdx.x] = s;
    red[1][threadIdx.x] = s2;
    __syncthreads();
    if (threadIdx.x < 128) {
        atomicAdd(&stats[col], red[0][threadIdx.x] + red[0][threadIdx.x + 128]);
        atomicAdd(&stats[128 + col], red[1][threadIdx.x] + red[1][threadIdx.x + 128]);
    }
}

__global__ void bn_finalize_k(const float* __restrict__ g, const float* __restrict__ be,
                              float* __restrict__ stats, int N) {
    int c = threadIdx.x;
    if (c < 128) {
        float mu = stats[c] / (float)N;
        float var = stats[128 + c] / (float)N - mu * mu;
        float sc = g[c] * rsqrtf(var + BN_EPS);
        stats[256 + c] = sc;
        stats[384 + c] = be[c] - mu * sc;
    }
}

__global__ void bn_apply_k(float* __restrict__ h, const float* __restrict__ stats, long long total4) {
    long long i = (long long)blockIdx.x * blockDim.x + threadIdx.x;
    long long stride = (long long)gridDim.x * blockDim.x;
    const float* sc = stats + 256;
    const float* sh = stats + 384;
    for (; i < total4; i += stride) {
        int c0 = (int)(i & 31) * 4;
        float4 v = ((float4*)h)[i];
        v.x = fmaxf(v.x * sc[c0 + 0] + sh[c0 + 0], 0.f);
        v.y = fmaxf(v.y * sc[c0 + 1] + sh[c0 + 1], 0.f);
        v.z = fmaxf(v.z * sc[c0 + 2] + sh[c0 + 2], 0.f);
        v.w = fmaxf(v.w * sc[c0 + 3] + sh[c0 + 3], 0.f);
        ((float4*)h)[i] = v;
    }
}

// ---------------- layer 2 scalar trick ----------------
// p[n] = h1[n] . Wl2
__global__ void gemv_p_k(const float* __restrict__ h, const float* __restrict__ Wl2,
                         float* __restrict__ p, int N) {
    const int lane = threadIdx.x & 63;
    const int n = (int)((blockIdx.x * (long long)blockDim.x + threadIdx.x) >> 6);
    if (n >= N) return;
    float2 w = ((const float2*)Wl2)[lane];
    float2 v = ((const float2*)(h + (size_t)n * 128))[lane];
    float s = v.x * w.x + v.y * w.y;
#pragma unroll
    for (int o = 32; o; o >>= 1) s += __shfl_down(s, o);
    if (lane == 0) p[n] = s;
}

// out[n] = sigmoid(((mean_agg p)[n] + h1[n].Wr2 + bl2)*wF + bF)
__global__ void layer2_final_k(const float* __restrict__ h, const float* __restrict__ p,
                               const int* __restrict__ csr, const int* __restrict__ off,
                               const int* __restrict__ endp, const float* __restrict__ inv,
                               const float* __restrict__ Wr2, const float* __restrict__ bl2,
                               const float* __restrict__ wF, const float* __restrict__ bF,
                               float* __restrict__ out, int N) {
    const int lane = threadIdx.x & 63;
    const int n = (int)((blockIdx.x * (long long)blockDim.x + threadIdx.x) >> 6);
    if (n >= N) return;
    float2 w = ((const float2*)Wr2)[lane];
    float2 v = ((const float2*)(h + (size_t)n * 128))[lane];
    float dotp = v.x * w.x + v.y * w.y;
    float ps = 0.f;
    const int o = off[n], e_end = endp[n];
    for (int e = o + lane; e < e_end; e += 64) ps += p[csr[e]];
    float s = dotp + ps * inv[n];
#pragma unroll
    for (int ow = 32; ow; ow >>= 1) s += __shfl_down(s, ow);
    if (lane == 0) {
        float z = (s + bl2[0]) * wF[0] + bF[0];
        out[n] = 1.f / (1.f + expf(-z));
    }
}

extern "C" void kernel_launch(void* const* d_in, const int* in_sizes, int n_in,
                              void* d_out, int out_size, void* d_ws, size_t ws_size,
                              hipStream_t stream) {
    const float* x   = (const float*)d_in[0];
    const int*   ei  = (const int*)d_in[1];
    const int E = in_sizes[1] / 2;
    const int N = in_sizes[0] / 64;
    const int* src = ei;
    const int* dst = ei + E;
    const float* Wl0 = (const float*)d_in[2];
    const float* bl0 = (const float*)d_in[3];
    const float* Wr0 = (const float*)d_in[4];
    const float* Wl1 = (const float*)d_in[5];
    const float* bl1 = (const float*)d_in[6];
    const float* Wr1 = (const float*)d_in[7];
    const float* Wl2 = (const float*)d_in[8];
    const float* bl2 = (const float*)d_in[9];
    const float* Wr2 = (const float*)d_in[10];
    const float* g0  = (const float*)d_in[11];
    const float* be0 = (const float*)d_in[12];
    const float* g1  = (const float*)d_in[13];
    const float* be1 = (const float*)d_in[14];
    const float* wF  = (const float*)d_in[15];
    const float* bF  = (const float*)d_in[16];

    float* A     = (float*)d_ws;                 // agg       [N,128]
    float* B     = A + (size_t)N * 128;          // h buffer  [N,128]
    int*   cnt   = (int*)(B + (size_t)N * 128);  // [N]  (reused as p after scan)
    int*   off   = cnt + N;                      // [N]
    int*   cursor= off + N;                      // [N] (= row end after fill)
    float* inv   = (float*)(cursor + N);         // [N]
    int*   csr   = (int*)(inv + N);              // [E]
    float* stats = (float*)(csr + E);            // [512]
    float* p     = (float*)cnt;                  // [N] alias, valid after scan
    float* out = (float*)d_out;

    const int gemm_grid = (N + 31) / 32;
    const int wave_grid = (N + 3) / 4;           // 4 waves (nodes) per 256-block

    // ---- CSR build
    hipMemsetAsync(cnt, 0, (size_t)N * sizeof(int), stream);
    count_edges_k<<<2048, 256, 0, stream>>>(dst, E, cnt);
    scan_k<<<1, 1024, 0, stream>>>(cnt, off, cursor, inv, N);
    csr_fill_k<<<2048, 256, 0, stream>>>(src, dst, E, cursor, csr);

    // ---- layer 0: x[N,64] -> B[N,128]
    gather_agg_k<64><<<wave_grid, 256, 0, stream>>>(x, csr, off, cursor, inv, A, N);
    sage_gemm_k<64><<<gemm_grid, 256, 0, stream>>>(A, x, Wl0, Wr0, bl0, B, N);
    hipMemsetAsync(stats, 0, 256 * sizeof(float), stream);
    bn_stats_k<<<512, 256, 0, stream>>>(B, N, stats);
    bn_finalize_k<<<1, 128, 0, stream>>>(g0, be0, stats, N);
    bn_apply_k<<<2048, 256, 0, stream>>>(B, stats, (long long)N * 32);

    // ---- layer 1: B[N,128] -> B[N,128] (in place)
    gather_agg_k<128><<<wave_grid, 256, 0, stream>>>(B, csr, off, cursor, inv, A, N);
    sage_gemm_k<128><<<gemm_grid, 256, 0, stream>>>(A, B, Wl1, Wr1, bl1, B, N);
    hipMemsetAsync(stats, 0, 256 * sizeof(float), stream);
    bn_stats_k<<<512, 256, 0, stream>>>(B, N, stats);
    bn_finalize_k<<<1, 128, 0, stream>>>(g1, be1, stats, N);
    bn_apply_k<<<2048, 256, 0, stream>>>(B, stats, (long long)N * 32);

    // ---- layer 2 via scalar trick: p = B@Wl2, out = sigmoid((agg_p*inv + B@Wr2 + bl2)*wF + bF)
    gemv_p_k<<<wave_grid, 256, 0, stream>>>(B, Wl2, p, N);
    layer2_final_k<<<wave_grid, 256, 0, stream>>>(B, p, csr, off, cursor, inv,
                                                  Wr2, bl2, wF, bF, out, N);
}

// Round 3
// 821.486 us; speedup vs baseline: 8.7654x; 1.2176x over previous
//
#include <hip/hip_runtime.h>
#include <math.h>

#define BN_EPS 1e-5f
#define SCAN_CHUNK 4096

// ---------------- degree count ----------------
__global__ void count_edges_k(const int* __restrict__ dst, int E, int* __restrict__ cnt) {
    int i = blockIdx.x * blockDim.x + threadIdx.x;
    int stride = gridDim.x * blockDim.x;
    for (int e = i; e < E; e += stride) atomicAdd(&cnt[dst[e]], 1);
}

// ---------------- hierarchical scan ----------------
__device__ __forceinline__ int wave_incl_scan(int v, int lane) {
#pragma unroll
    for (int d = 1; d < 64; d <<= 1) {
        int u = __shfl_up(v, d);
        if (lane >= d) v += u;
    }
    return v;
}

// pass 1: per-block (4096-elem chunk) sum
__global__ void block_sum_k(const int* __restrict__ cnt, int N, int* __restrict__ bsum) {
    const int t = threadIdx.x;
    const int base = blockIdx.x * SCAN_CHUNK;
    int s = 0;
    for (int i = t; i < SCAN_CHUNK; i += 256) {
        int idx = base + i;
        if (idx < N) s += cnt[idx];
    }
    const int lane = t & 63, wid = t >> 6;
#pragma unroll
    for (int d = 32; d; d >>= 1) s += __shfl_down(s, d);
    __shared__ int ws[4];
    if (lane == 0) ws[wid] = s;
    __syncthreads();
    if (t == 0) bsum[blockIdx.x] = ws[0] + ws[1] + ws[2] + ws[3];
}

// pass 2: exclusive-scan the (<=64) block sums in a single wave
__global__ void scan_bsums_k(int* __restrict__ bsum, int nb) {
    int lane = threadIdx.x;
    int v = (lane < nb) ? bsum[lane] : 0;
    int incl = wave_incl_scan(v, lane);
    if (lane < nb) bsum[lane] = incl - v;
}

// pass 3: per-block local scan + global offset; write off/cursor/inv
__global__ void scan_write_k(const int* __restrict__ cnt, const int* __restrict__ bsum, int N,
                             int* __restrict__ off, int* __restrict__ cursor,
                             float* __restrict__ inv) {
    const int t = threadIdx.x;
    const int base = blockIdx.x * SCAN_CHUNK;
    const int idx0 = base + t * 16;
    int pre[16];
    int s = 0;
#pragma unroll
    for (int j = 0; j < 16; ++j) {
        int i = idx0 + j;
        int c = (i < N) ? cnt[i] : 0;
        pre[j] = s;
        s += c;
    }
    const int lane = t & 63, wid = t >> 6;
    int incl = wave_incl_scan(s, lane);
    __shared__ int ws[4];
    if (lane == 63) ws[wid] = incl;
    __syncthreads();
    if (t == 0) {
        int a = 0;
#pragma unroll
        for (int w = 0; w < 4; ++w) { int tmp = ws[w]; ws[w] = a; a += tmp; }
    }
    __syncthreads();
    const int tbase = bsum[blockIdx.x] + (incl - s) + ws[wid];
#pragma unroll
    for (int j = 0; j < 16; ++j) {
        int i = idx0 + j;
        if (i < N) {
            int c = cnt[i];
            int o = tbase + pre[j];
            off[i] = o;
            cursor[i] = o;
            inv[i] = 1.0f / fmaxf((float)c, 1.0f);
        }
    }
}

// ---------------- CSR fill (cursor ends at row end) ----------------
__global__ void csr_fill_k(const int* __restrict__ src, const int* __restrict__ dst, int E,
                           int* __restrict__ cursor, int* __restrict__ csr) {
    int i = blockIdx.x * blockDim.x + threadIdx.x;
    int stride = gridDim.x * blockDim.x;
    for (int e = i; e < E; e += stride) {
        int d = dst[e];
        int pos = atomicAdd(&cursor[d], 1);
        csr[pos] = src[e];
    }
}

// ---------------- gather-mean aggregation ----------------
template<int C>
__global__ void gather_agg_k(const float* __restrict__ feat, const int* __restrict__ csr,
                             const int* __restrict__ off, const int* __restrict__ endp,
                             const float* __restrict__ inv, float* __restrict__ agg, int N) {
    const int lane = threadIdx.x & 63;
    const int n = (int)((blockIdx.x * (long long)blockDim.x + threadIdx.x) >> 6);
    if (n >= N) return;
    const int o = off[n];
    const int e_end = endp[n];
    float acc0 = 0.f, acc1 = 0.f;
    int e = o;
    if constexpr (C == 128) {
        for (; e + 1 < e_end; e += 2) {
            int s0 = csr[e], s1 = csr[e + 1];
            float2 v0 = ((const float2*)(feat + (size_t)s0 * 128))[lane];
            float2 v1 = ((const float2*)(feat + (size_t)s1 * 128))[lane];
            acc0 += v0.x + v1.x;
            acc1 += v0.y + v1.y;
        }
        if (e < e_end) {
            float2 v = ((const float2*)(feat + (size_t)csr[e] * 128))[lane];
            acc0 += v.x; acc1 += v.y;
        }
        float iv = inv[n];
        float2 r; r.x = acc0 * iv; r.y = acc1 * iv;
        ((float2*)(agg + (size_t)n * 128))[lane] = r;
    } else {
        for (; e + 1 < e_end; e += 2) {
            int s0 = csr[e], s1 = csr[e + 1];
            acc0 += feat[(size_t)s0 * C + lane];
            acc1 += feat[(size_t)s1 * C + lane];
        }
        if (e < e_end) acc0 += feat[(size_t)csr[e] * C + lane];
        agg[(size_t)n * C + lane] = (acc0 + acc1) * inv[n];
    }
}

// ---------------- fused SAGE gemm: out = agg@Wl + xin@Wr + bl (agg pre-scaled) ----------------
template<int K>
__launch_bounds__(256)
__global__ void sage_gemm_k(const float* __restrict__ agg, const float* xin,
                            const float* __restrict__ Wl, const float* __restrict__ Wr,
                            const float* __restrict__ bl, float* out, int N) {
    constexpr int ROWS = 32;
    __shared__ float sA[ROWS][K];
    __shared__ float sX[ROWS][K];
    const int t = threadIdx.x;
    const int rowbase = blockIdx.x * ROWS;

    constexpr int J = K / 4;
    constexpr int ELEMS4 = ROWS * J;
    const float4* a4 = (const float4*)(agg + (size_t)rowbase * K);
    const float4* x4 = (const float4*)(xin + (size_t)rowbase * K);
    float4* sA4 = (float4*)sA;
    float4* sX4 = (float4*)sX;
    for (int i = t; i < ELEMS4; i += 256) {
        int r = i / J;
        if (rowbase + r < N) {
            sA4[i] = a4[i];
            sX4[i] = x4[i];
        }
    }
    __syncthreads();

    const int col = t & 127;
    const int rh = t >> 7;
    const int rb = rh * (ROWS / 2);
    float acc[ROWS / 2];
    const float b = bl[col];
#pragma unroll
    for (int r = 0; r < ROWS / 2; ++r) acc[r] = b;

    for (int k4 = 0; k4 < K; k4 += 4) {
        float wl0 = Wl[(k4 + 0) * 128 + col];
        float wl1 = Wl[(k4 + 1) * 128 + col];
        float wl2 = Wl[(k4 + 2) * 128 + col];
        float wl3 = Wl[(k4 + 3) * 128 + col];
        float wr0 = Wr[(k4 + 0) * 128 + col];
        float wr1 = Wr[(k4 + 1) * 128 + col];
        float wr2 = Wr[(k4 + 2) * 128 + col];
        float wr3 = Wr[(k4 + 3) * 128 + col];
#pragma unroll
        for (int r = 0; r < ROWS / 2; ++r) {
            float4 a = *(const float4*)&sA[rb + r][k4];
            float4 x = *(const float4*)&sX[rb + r][k4];
            acc[r] += a.x * wl0 + a.y * wl1 + a.z * wl2 + a.w * wl3
                    + x.x * wr0 + x.y * wr1 + x.z * wr2 + x.w * wr3;
        }
    }

#pragma unroll
    for (int r = 0; r < ROWS / 2; ++r) {
        int row = rowbase + rb + r;
        if (row < N) out[(size_t)row * 128 + col] = acc[r];
    }
}

// ---------------- BN stats ----------------
__global__ void bn_stats_k(const float* __restrict__ h, int N, float* __restrict__ stats) {
    const int col = threadIdx.x & 127;
    const int part = threadIdx.x >> 7;
    float s = 0.f, s2 = 0.f;
    for (int r = blockIdx.x * 2 + part; r < N; r += gridDim.x * 2) {
        float v = h[(size_t)r * 128 + col];
        s += v;
        s2 += v * v;
    }
    __shared__ float red[2][256];
    red[0][threadIdx.x] = s;
    red[1][threadIdx.x] = s2;
    __syncthreads();
    if (threadIdx.x < 128) {
        atomicAdd(&stats[col], red[0][threadIdx.x] + red[0][threadIdx.x + 128]);
        atomicAdd(&stats[128 + col], red[1][threadIdx.x] + red[1][threadIdx.x + 128]);
    }
}

__global__ void bn_finalize_k(const float* __restrict__ g, const float* __restrict__ be,
                              float* __restrict__ stats, int N) {
    int c = threadIdx.x;
    if (c < 128) {
        float mu = stats[c] / (float)N;
        float var = stats[128 + c] / (float)N - mu * mu;
        float sc = g[c] * rsqrtf(var + BN_EPS);
        stats[256 + c] = sc;
        stats[384 + c] = be[c] - mu * sc;
    }
}

__global__ void bn_apply_k(float* __restrict__ h, const float* __restrict__ stats, long long total4) {
    long long i = (long long)blockIdx.x * blockDim.x + threadIdx.x;
    long long stride = (long long)gridDim.x * blockDim.x;
    const float* sc = stats + 256;
    const float* sh = stats + 384;
    for (; i < total4; i += stride) {
        int c0 = (int)(i & 31) * 4;
        float4 v = ((float4*)h)[i];
        v.x = fmaxf(v.x * sc[c0 + 0] + sh[c0 + 0], 0.f);
        v.y = fmaxf(v.y * sc[c0 + 1] + sh[c0 + 1], 0.f);
        v.z = fmaxf(v.z * sc[c0 + 2] + sh[c0 + 2], 0.f);
        v.w = fmaxf(v.w * sc[c0 + 3] + sh[c0 + 3], 0.f);
        ((float4*)h)[i] = v;
    }
}

// ---------------- fused BN apply + p = h.Wl2 (wave-per-node) ----------------
__global__ void bn_apply_p_k(float* __restrict__ h, const float* __restrict__ stats,
                             const float* __restrict__ Wl2, float* __restrict__ p, int N) {
    const int lane = threadIdx.x & 63;
    const int n = (int)((blockIdx.x * (long long)blockDim.x + threadIdx.x) >> 6);
    if (n >= N) return;
    const float2 sc = ((const float2*)(stats + 256))[lane];
    const float2 sh = ((const float2*)(stats + 384))[lane];
    const float2 w  = ((const float2*)Wl2)[lane];
    float2 v = ((float2*)(h + (size_t)n * 128))[lane];
    v.x = fmaxf(v.x * sc.x + sh.x, 0.f);
    v.y = fmaxf(v.y * sc.y + sh.y, 0.f);
    ((float2*)(h + (size_t)n * 128))[lane] = v;
    float s = v.x * w.x + v.y * w.y;
#pragma unroll
    for (int o = 32; o; o >>= 1) s += __shfl_down(s, o);
    if (lane == 0) p[n] = s;
}

// ---------------- layer 2 final ----------------
__global__ void layer2_final_k(const float* __restrict__ h, const float* __restrict__ p,
                               const int* __restrict__ csr, const int* __restrict__ off,
                               const int* __restrict__ endp, const float* __restrict__ inv,
                               const float* __restrict__ Wr2, const float* __restrict__ bl2,
                               const float* __restrict__ wF, const float* __restrict__ bF,
                               float* __restrict__ out, int N) {
    const int lane = threadIdx.x & 63;
    const int n = (int)((blockIdx.x * (long long)blockDim.x + threadIdx.x) >> 6);
    if (n >= N) return;
    float2 w = ((const float2*)Wr2)[lane];
    float2 v = ((const float2*)(h + (size_t)n * 128))[lane];
    float dotp = v.x * w.x + v.y * w.y;
    float ps = 0.f;
    const int o = off[n], e_end = endp[n];
    for (int e = o + lane; e < e_end; e += 64) ps += p[csr[e]];
    float s = dotp + ps * inv[n];
#pragma unroll
    for (int ow = 32; ow; ow >>= 1) s += __shfl_down(s, ow);
    if (lane == 0) {
        float z = (s + bl2[0]) * wF[0] + bF[0];
        out[n] = 1.f / (1.f + expf(-z));
    }
}

extern "C" void kernel_launch(void* const* d_in, const int* in_sizes, int n_in,
                              void* d_out, int out_size, void* d_ws, size_t ws_size,
                              hipStream_t stream) {
    const float* x   = (const float*)d_in[0];
    const int*   ei  = (const int*)d_in[1];
    const int E = in_sizes[1] / 2;
    const int N = in_sizes[0] / 64;
    const int* src = ei;
    const int* dst = ei + E;
    const float* Wl0 = (const float*)d_in[2];
    const float* bl0 = (const float*)d_in[3];
    const float* Wr0 = (const float*)d_in[4];
    const float* Wl1 = (const float*)d_in[5];
    const float* bl1 = (const float*)d_in[6];
    const float* Wr1 = (const float*)d_in[7];
    const float* Wl2 = (const float*)d_in[8];
    const float* bl2 = (const float*)d_in[9];
    const float* Wr2 = (const float*)d_in[10];
    const float* g0  = (const float*)d_in[11];
    const float* be0 = (const float*)d_in[12];
    const float* g1  = (const float*)d_in[13];
    const float* be1 = (const float*)d_in[14];
    const float* wF  = (const float*)d_in[15];
    const float* bF  = (const float*)d_in[16];

    float* A     = (float*)d_ws;                 // agg       [N,128]
    float* B     = A + (size_t)N * 128;          // h buffer  [N,128]
    int*   cnt   = (int*)(B + (size_t)N * 128);  // [N]  (reused as p later)
    int*   off   = cnt + N;                      // [N]
    int*   cursor= off + N;                      // [N] (= row end after fill)
    float* inv   = (float*)(cursor + N);         // [N]
    int*   csr   = (int*)(inv + N);              // [E]
    float* stats = (float*)(csr + E);            // [512]
    int*   bsum  = (int*)(stats + 512);          // [64]
    float* p     = (float*)cnt;                  // [N] alias, valid after scan_write
    float* out = (float*)d_out;

    const int gemm_grid = (N + 31) / 32;
    const int wave_grid = (N + 3) / 4;
    const int nb = (N + SCAN_CHUNK - 1) / SCAN_CHUNK;

    // ---- CSR build
    hipMemsetAsync(cnt, 0, (size_t)N * sizeof(int), stream);
    count_edges_k<<<2048, 256, 0, stream>>>(dst, E, cnt);
    block_sum_k<<<nb, 256, 0, stream>>>(cnt, N, bsum);
    scan_bsums_k<<<1, 64, 0, stream>>>(bsum, nb);
    scan_write_k<<<nb, 256, 0, stream>>>(cnt, bsum, N, off, cursor, inv);
    csr_fill_k<<<2048, 256, 0, stream>>>(src, dst, E, cursor, csr);

    // ---- layer 0: x[N,64] -> B[N,128]
    gather_agg_k<64><<<wave_grid, 256, 0, stream>>>(x, csr, off, cursor, inv, A, N);
    sage_gemm_k<64><<<gemm_grid, 256, 0, stream>>>(A, x, Wl0, Wr0, bl0, B, N);
    hipMemsetAsync(stats, 0, 256 * sizeof(float), stream);
    bn_stats_k<<<512, 256, 0, stream>>>(B, N, stats);
    bn_finalize_k<<<1, 128, 0, stream>>>(g0, be0, stats, N);
    bn_apply_k<<<2048, 256, 0, stream>>>(B, stats, (long long)N * 32);

    // ---- layer 1: B[N,128] -> B[N,128] (in place)
    gather_agg_k<128><<<wave_grid, 256, 0, stream>>>(B, csr, off, cursor, inv, A, N);
    sage_gemm_k<128><<<gemm_grid, 256, 0, stream>>>(A, B, Wl1, Wr1, bl1, B, N);
    hipMemsetAsync(stats, 0, 256 * sizeof(float), stream);
    bn_stats_k<<<512, 256, 0, stream>>>(B, N, stats);
    bn_finalize_k<<<1, 128, 0, stream>>>(g1, be1, stats, N);
    // fused BN apply + p = B@Wl2  (p aliases cnt, no longer needed)
    bn_apply_p_k<<<wave_grid, 256, 0, stream>>>(B, stats, Wl2, p, N);

    // ---- layer 2 via scalar trick
    layer2_final_k<<<wave_grid, 256, 0, stream>>>(B, p, csr, off, cursor, inv,
                                                  Wr2, bl2, wF, bF, out, N);
}

// Round 4
// 636.659 us; speedup vs baseline: 11.3101x; 1.2903x over previous
//
#include <hip/hip_runtime.h>
#include <math.h>

#define BN_EPS 1e-5f
#define SCAN_CHUNK 4096

typedef __attribute__((ext_vector_type(8))) short bf16x8;
typedef __attribute__((ext_vector_type(4))) float f32x4;

// RNE fp32 -> bf16
__device__ __forceinline__ unsigned short f2bf(float f) {
    unsigned int u = __float_as_uint(f);
    u = (u + 0x7fffu + ((u >> 16) & 1u)) >> 16;
    return (unsigned short)u;
}

// ---------------- degree count ----------------
__global__ void count_edges_k(const int* __restrict__ dst, int E, int* __restrict__ cnt) {
    int i = blockIdx.x * blockDim.x + threadIdx.x;
    int stride = gridDim.x * blockDim.x;
    for (int e = i; e < E; e += stride) atomicAdd(&cnt[dst[e]], 1);
}

// ---------------- hierarchical scan ----------------
__device__ __forceinline__ int wave_incl_scan(int v, int lane) {
#pragma unroll
    for (int d = 1; d < 64; d <<= 1) {
        int u = __shfl_up(v, d);
        if (lane >= d) v += u;
    }
    return v;
}

__global__ void block_sum_k(const int* __restrict__ cnt, int N, int* __restrict__ bsum) {
    const int t = threadIdx.x;
    const int base = blockIdx.x * SCAN_CHUNK;
    int s = 0;
    for (int i = t; i < SCAN_CHUNK; i += 256) {
        int idx = base + i;
        if (idx < N) s += cnt[idx];
    }
    const int lane = t & 63, wid = t >> 6;
#pragma unroll
    for (int d = 32; d; d >>= 1) s += __shfl_down(s, d);
    __shared__ int ws[4];
    if (lane == 0) ws[wid] = s;
    __syncthreads();
    if (t == 0) bsum[blockIdx.x] = ws[0] + ws[1] + ws[2] + ws[3];
}

__global__ void scan_bsums_k(int* __restrict__ bsum, int nb) {
    int lane = threadIdx.x;
    int v = (lane < nb) ? bsum[lane] : 0;
    int incl = wave_incl_scan(v, lane);
    if (lane < nb) bsum[lane] = incl - v;
}

__global__ void scan_write_k(const int* __restrict__ cnt, const int* __restrict__ bsum, int N,
                             int* __restrict__ off, int* __restrict__ cursor,
                             float* __restrict__ inv) {
    const int t = threadIdx.x;
    const int base = blockIdx.x * SCAN_CHUNK;
    const int idx0 = base + t * 16;
    int pre[16];
    int s = 0;
#pragma unroll
    for (int j = 0; j < 16; ++j) {
        int i = idx0 + j;
        int c = (i < N) ? cnt[i] : 0;
        pre[j] = s;
        s += c;
    }
    const int lane = t & 63, wid = t >> 6;
    int incl = wave_incl_scan(s, lane);
    __shared__ int ws[4];
    if (lane == 63) ws[wid] = incl;
    __syncthreads();
    if (t == 0) {
        int a = 0;
#pragma unroll
        for (int w = 0; w < 4; ++w) { int tmp = ws[w]; ws[w] = a; a += tmp; }
    }
    __syncthreads();
    const int tbase = bsum[blockIdx.x] + (incl - s) + ws[wid];
#pragma unroll
    for (int j = 0; j < 16; ++j) {
        int i = idx0 + j;
        if (i < N) {
            int c = cnt[i];
            int o = tbase + pre[j];
            off[i] = o;
            cursor[i] = o;
            inv[i] = 1.0f / fmaxf((float)c, 1.0f);
        }
    }
}

// ---------------- CSR fill ----------------
__global__ void csr_fill_k(const int* __restrict__ src, const int* __restrict__ dst, int E,
                           int* __restrict__ cursor, int* __restrict__ csr) {
    int i = blockIdx.x * blockDim.x + threadIdx.x;
    int stride = gridDim.x * blockDim.x;
    for (int e = i; e < E; e += stride) {
        int d = dst[e];
        int pos = atomicAdd(&cursor[d], 1);
        csr[pos] = src[e];
    }
}

// ---------------- gather-mean aggregation ----------------
template<int C>
__global__ void gather_agg_k(const float* __restrict__ feat, const int* __restrict__ csr,
                             const int* __restrict__ off, const int* __restrict__ endp,
                             const float* __restrict__ inv, float* __restrict__ agg, int N) {
    const int lane = threadIdx.x & 63;
    const int n = (int)((blockIdx.x * (long long)blockDim.x + threadIdx.x) >> 6);
    if (n >= N) return;
    const int o = off[n];
    const int e_end = endp[n];
    float acc0 = 0.f, acc1 = 0.f;
    int e = o;
    if constexpr (C == 128) {
        for (; e + 1 < e_end; e += 2) {
            int s0 = csr[e], s1 = csr[e + 1];
            float2 v0 = ((const float2*)(feat + (size_t)s0 * 128))[lane];
            float2 v1 = ((const float2*)(feat + (size_t)s1 * 128))[lane];
            acc0 += v0.x + v1.x;
            acc1 += v0.y + v1.y;
        }
        if (e < e_end) {
            float2 v = ((const float2*)(feat + (size_t)csr[e] * 128))[lane];
            acc0 += v.x; acc1 += v.y;
        }
        float iv = inv[n];
        float2 r; r.x = acc0 * iv; r.y = acc1 * iv;
        ((float2*)(agg + (size_t)n * 128))[lane] = r;
    } else {
        for (; e + 1 < e_end; e += 2) {
            int s0 = csr[e], s1 = csr[e + 1];
            acc0 += feat[(size_t)s0 * C + lane];
            acc1 += feat[(size_t)s1 * C + lane];
        }
        if (e < e_end) acc0 += feat[(size_t)csr[e] * C + lane];
        agg[(size_t)n * C + lane] = (acc0 + acc1) * inv[n];
    }
}

// ---------------- weight pre-pack into MFMA B-fragment order (bf16) ----------------
// B = [Wl ; Wr] (KT x 128). frag element: lane l, elem j of chunk q=(ct*KIT+kit)
// holds B[kit*32 + (l>>4)*8 + j][ct*16 + (l&15)].
__global__ void wfrag_build_k(const float* __restrict__ Wl, const float* __restrict__ Wr,
                              int CIN, int KIT, unsigned short* __restrict__ wf) {
    int t = blockIdx.x * blockDim.x + threadIdx.x;
    int lane = t & 63;
    int q = t >> 6;
    if (q >= 8 * KIT) return;
    int kit = q % KIT;
    int ct = q / KIT;
    int col = ct * 16 + (lane & 15);
    bf16x8 v;
#pragma unroll
    for (int j = 0; j < 8; ++j) {
        int kg = kit * 32 + ((lane >> 4) << 3) + j;
        float f = (kg < CIN) ? Wl[(size_t)kg * 128 + col] : Wr[(size_t)(kg - CIN) * 128 + col];
        v[j] = (short)f2bf(f);
    }
    ((bf16x8*)wf)[q * 64 + lane] = v;
}

// ---------------- MFMA SAGE gemm: out = [agg|xin](bf16) @ [Wl;Wr](bf16) + bl, fp32 acc ----
// 32 rows x 128 cols per block, 4 waves. out may alias xin (rows staged to LDS first).
template<int CIN>
__launch_bounds__(256)
__global__ void sage_gemm_mfma_k(const float* __restrict__ agg, const float* xin,
                                 const unsigned short* __restrict__ wfrag,
                                 const float* __restrict__ bl, float* out, int N) {
    constexpr int KT = 2 * CIN;
    constexpr int KIT = KT / 32;
    __shared__ unsigned short sA[32 * KT];   // [row][k] bf16, XOR-swizzled

    const int t = threadIdx.x;
    const int rowbase = blockIdx.x * 32;

    // stage + convert fp32 -> bf16
    constexpr int CH = CIN / 4;
    const float4* a4 = (const float4*)(agg + (size_t)rowbase * CIN);
    const float4* x4 = (const float4*)(xin + (size_t)rowbase * CIN);
    for (int i = t; i < 32 * CH; i += 256) {
        int row = i / CH, c4 = i % CH;
        if (rowbase + row < N) {
            float4 va = a4[i];
            float4 vx = x4[i];
            int swz = (row & 7) << 4;
            int ba = ((row * KT + c4 * 4) * 2) ^ swz;
            int bx = ((row * KT + CIN + c4 * 4) * 2) ^ swz;
            *(ushort4*)((char*)sA + ba) = make_ushort4(f2bf(va.x), f2bf(va.y), f2bf(va.z), f2bf(va.w));
            *(ushort4*)((char*)sA + bx) = make_ushort4(f2bf(vx.x), f2bf(vx.y), f2bf(vx.z), f2bf(vx.w));
        }
    }
    __syncthreads();

    const int wave = t >> 6, lane = t & 63;
    f32x4 acc00 = {0.f,0.f,0.f,0.f}, acc01 = acc00, acc10 = acc00, acc11 = acc00;

    const int koff = (lane >> 4) << 4;             // bytes
    const int swz = (lane & 7) << 4;               // row&7 == lane&7 for both row tiles
    const int base0 = (lane & 15) * KT * 2 + koff;
    const int base1 = (16 + (lane & 15)) * KT * 2 + koff;
    const bf16x8* wf8 = (const bf16x8*)wfrag;
    const int bq0 = (wave * 2 + 0) * KIT;
    const int bq1 = (wave * 2 + 1) * KIT;

#pragma unroll
    for (int kit = 0; kit < KIT; ++kit) {
        bf16x8 fa0 = *(const bf16x8*)((const char*)sA + ((base0 + kit * 64) ^ swz));
        bf16x8 fa1 = *(const bf16x8*)((const char*)sA + ((base1 + kit * 64) ^ swz));
        bf16x8 fb0 = wf8[(bq0 + kit) * 64 + lane];
        bf16x8 fb1 = wf8[(bq1 + kit) * 64 + lane];
        acc00 = __builtin_amdgcn_mfma_f32_16x16x32_bf16(fa0, fb0, acc00, 0, 0, 0);
        acc01 = __builtin_amdgcn_mfma_f32_16x16x32_bf16(fa0, fb1, acc01, 0, 0, 0);
        acc10 = __builtin_amdgcn_mfma_f32_16x16x32_bf16(fa1, fb0, acc10, 0, 0, 0);
        acc11 = __builtin_amdgcn_mfma_f32_16x16x32_bf16(fa1, fb1, acc11, 0, 0, 0);
    }

    // epilogue: C/D layout col=lane&15, row=(lane>>4)*4+reg
    const int c0 = wave * 32 + (lane & 15);
    const int c1 = c0 + 16;
    const float b0 = bl[c0], b1 = bl[c1];
#pragma unroll
    for (int r = 0; r < 4; ++r) {
        int row0 = rowbase + ((lane >> 4) << 2) + r;
        int row1 = row0 + 16;
        if (row0 < N) {
            out[(size_t)row0 * 128 + c0] = acc00[r] + b0;
            out[(size_t)row0 * 128 + c1] = acc01[r] + b1;
        }
        if (row1 < N) {
            out[(size_t)row1 * 128 + c0] = acc10[r] + b0;
            out[(size_t)row1 * 128 + c1] = acc11[r] + b1;
        }
    }
}

// ---------------- BN stats ----------------
__global__ void bn_stats_k(const float* __restrict__ h, int N, float* __restrict__ stats) {
    const int col = threadIdx.x & 127;
    const int part = threadIdx.x >> 7;
    float s = 0.f, s2 = 0.f;
    for (int r = blockIdx.x * 2 + part; r < N; r += gridDim.x * 2) {
        float v = h[(size_t)r * 128 + col];
        s += v;
        s2 += v * v;
    }
    __shared__ float red[2][256];
    red[0][threadIdx.x] = s;
    red[1][threadIdx.x] = s2;
    __syncthreads();
    if (threadIdx.x < 128) {
        atomicAdd(&stats[col], red[0][threadIdx.x] + red[0][threadIdx.x + 128]);
        atomicAdd(&stats[128 + col], red[1][threadIdx.x] + red[1][threadIdx.x + 128]);
    }
}

__global__ void bn_finalize_k(const float* __restrict__ g, const float* __restrict__ be,
                              float* __restrict__ stats, int N) {
    int c = threadIdx.x;
    if (c < 128) {
        float mu = stats[c] / (float)N;
        float var = stats[128 + c] / (float)N - mu * mu;
        float sc = g[c] * rsqrtf(var + BN_EPS);
        stats[256 + c] = sc;
        stats[384 + c] = be[c] - mu * sc;
    }
}

__global__ void bn_apply_k(float* __restrict__ h, const float* __restrict__ stats, long long total4) {
    long long i = (long long)blockIdx.x * blockDim.x + threadIdx.x;
    long long stride = (long long)gridDim.x * blockDim.x;
    const float* sc = stats + 256;
    const float* sh = stats + 384;
    for (; i < total4; i += stride) {
        int c0 = (int)(i & 31) * 4;
        float4 v = ((float4*)h)[i];
        v.x = fmaxf(v.x * sc[c0 + 0] + sh[c0 + 0], 0.f);
        v.y = fmaxf(v.y * sc[c0 + 1] + sh[c0 + 1], 0.f);
        v.z = fmaxf(v.z * sc[c0 + 2] + sh[c0 + 2], 0.f);
        v.w = fmaxf(v.w * sc[c0 + 3] + sh[c0 + 3], 0.f);
        ((float4*)h)[i] = v;
    }
}

// ---------------- fused BN apply + p = h.Wl2 ----------------
__global__ void bn_apply_p_k(float* __restrict__ h, const float* __restrict__ stats,
                             const float* __restrict__ Wl2, float* __restrict__ p, int N) {
    const int lane = threadIdx.x & 63;
    const int n = (int)((blockIdx.x * (long long)blockDim.x + threadIdx.x) >> 6);
    if (n >= N) return;
    const float2 sc = ((const float2*)(stats + 256))[lane];
    const float2 sh = ((const float2*)(stats + 384))[lane];
    const float2 w  = ((const float2*)Wl2)[lane];
    float2 v = ((float2*)(h + (size_t)n * 128))[lane];
    v.x = fmaxf(v.x * sc.x + sh.x, 0.f);
    v.y = fmaxf(v.y * sc.y + sh.y, 0.f);
    ((float2*)(h + (size_t)n * 128))[lane] = v;
    float s = v.x * w.x + v.y * w.y;
#pragma unroll
    for (int o = 32; o; o >>= 1) s += __shfl_down(s, o);
    if (lane == 0) p[n] = s;
}

// ---------------- layer 2 final ----------------
__global__ void layer2_final_k(const float* __restrict__ h, const float* __restrict__ p,
                               const int* __restrict__ csr, const int* __restrict__ off,
                               const int* __restrict__ endp, const float* __restrict__ inv,
                               const float* __restrict__ Wr2, const float* __restrict__ bl2,
                               const float* __restrict__ wF, const float* __restrict__ bF,
                               float* __restrict__ out, int N) {
    const int lane = threadIdx.x & 63;
    const int n = (int)((blockIdx.x * (long long)blockDim.x + threadIdx.x) >> 6);
    if (n >= N) return;
    float2 w = ((const float2*)Wr2)[lane];
    float2 v = ((const float2*)(h + (size_t)n * 128))[lane];
    float dotp = v.x * w.x + v.y * w.y;
    float ps = 0.f;
    const int o = off[n], e_end = endp[n];
    for (int e = o + lane; e < e_end; e += 64) ps += p[csr[e]];
    float s = dotp + ps * inv[n];
#pragma unroll
    for (int ow = 32; ow; ow >>= 1) s += __shfl_down(s, ow);
    if (lane == 0) {
        float z = (s + bl2[0]) * wF[0] + bF[0];
        out[n] = 1.f / (1.f + expf(-z));
    }
}

extern "C" void kernel_launch(void* const* d_in, const int* in_sizes, int n_in,
                              void* d_out, int out_size, void* d_ws, size_t ws_size,
                              hipStream_t stream) {
    const float* x   = (const float*)d_in[0];
    const int*   ei  = (const int*)d_in[1];
    const int E = in_sizes[1] / 2;
    const int N = in_sizes[0] / 64;
    const int* src = ei;
    const int* dst = ei + E;
    const float* Wl0 = (const float*)d_in[2];
    const float* bl0 = (const float*)d_in[3];
    const float* Wr0 = (const float*)d_in[4];
    const float* Wl1 = (const float*)d_in[5];
    const float* bl1 = (const float*)d_in[6];
    const float* Wr1 = (const float*)d_in[7];
    const float* Wl2 = (const float*)d_in[8];
    const float* bl2 = (const float*)d_in[9];
    const float* Wr2 = (const float*)d_in[10];
    const float* g0  = (const float*)d_in[11];
    const float* be0 = (const float*)d_in[12];
    const float* g1  = (const float*)d_in[13];
    const float* be1 = (const float*)d_in[14];
    const float* wF  = (const float*)d_in[15];
    const float* bF  = (const float*)d_in[16];

    float* A     = (float*)d_ws;                 // agg       [N,128]
    float* B     = A + (size_t)N * 128;          // h buffer  [N,128]
    int*   cnt   = (int*)(B + (size_t)N * 128);  // [N]  (reused as p later)
    int*   off   = cnt + N;                      // [N]
    int*   cursor= off + N;                      // [N] (= row end after fill)
    float* inv   = (float*)(cursor + N);         // [N]
    int*   csr   = (int*)(inv + N);              // [E]
    float* stats = (float*)(csr + E);            // [512]
    int*   bsum  = (int*)(stats + 512);          // [64]
    unsigned short* wf0 = (unsigned short*)(bsum + 64);      // [8*4*64*8]  = 16K bf16
    unsigned short* wf1 = wf0 + 8 * 4 * 64 * 8;              // [8*8*64*8]  = 32K bf16
    float* p     = (float*)cnt;                  // [N] alias, valid after scan_write
    float* out = (float*)d_out;

    const int gemm_grid = (N + 31) / 32;
    const int wave_grid = (N + 3) / 4;
    const int nb = (N + SCAN_CHUNK - 1) / SCAN_CHUNK;

    // ---- weight pre-pack (independent of graph work)
    wfrag_build_k<<<(8 * 4 * 64 + 255) / 256, 256, 0, stream>>>(Wl0, Wr0, 64, 4, wf0);
    wfrag_build_k<<<(8 * 8 * 64 + 255) / 256, 256, 0, stream>>>(Wl1, Wr1, 128, 8, wf1);

    // ---- CSR build
    hipMemsetAsync(cnt, 0, (size_t)N * sizeof(int), stream);
    count_edges_k<<<2048, 256, 0, stream>>>(dst, E, cnt);
    block_sum_k<<<nb, 256, 0, stream>>>(cnt, N, bsum);
    scan_bsums_k<<<1, 64, 0, stream>>>(bsum, nb);
    scan_write_k<<<nb, 256, 0, stream>>>(cnt, bsum, N, off, cursor, inv);
    csr_fill_k<<<2048, 256, 0, stream>>>(src, dst, E, cursor, csr);

    // ---- layer 0: x[N,64] -> B[N,128]
    gather_agg_k<64><<<wave_grid, 256, 0, stream>>>(x, csr, off, cursor, inv, A, N);
    sage_gemm_mfma_k<64><<<gemm_grid, 256, 0, stream>>>(A, x, wf0, bl0, B, N);
    hipMemsetAsync(stats, 0, 256 * sizeof(float), stream);
    bn_stats_k<<<512, 256, 0, stream>>>(B, N, stats);
    bn_finalize_k<<<1, 128, 0, stream>>>(g0, be0, stats, N);
    bn_apply_k<<<2048, 256, 0, stream>>>(B, stats, (long long)N * 32);

    // ---- layer 1: B[N,128] -> B[N,128] (in place)
    gather_agg_k<128><<<wave_grid, 256, 0, stream>>>(B, csr, off, cursor, inv, A, N);
    sage_gemm_mfma_k<128><<<gemm_grid, 256, 0, stream>>>(A, B, wf1, bl1, B, N);
    hipMemsetAsync(stats, 0, 256 * sizeof(float), stream);
    bn_stats_k<<<512, 256, 0, stream>>>(B, N, stats);
    bn_finalize_k<<<1, 128, 0, stream>>>(g1, be1, stats, N);
    // fused BN apply + p = B@Wl2
    bn_apply_p_k<<<wave_grid, 256, 0, stream>>>(B, stats, Wl2, p, N);

    // ---- layer 2 via scalar trick
    layer2_final_k<<<wave_grid, 256, 0, stream>>>(B, p, csr, off, cursor, inv,
                                                  Wr2, bl2, wF, bF, out, N);
}

// Round 5
// 566.671 us; speedup vs baseline: 12.7070x; 1.1235x over previous
//
#include <hip/hip_runtime.h>
#include <math.h>

#define BN_EPS 1e-5f
#define SCAN_CHUNK 4096

typedef __attribute__((ext_vector_type(8))) short bf16x8;
typedef __attribute__((ext_vector_type(4))) float f32x4;

// RNE fp32 -> bf16 (bit pattern)
__device__ __forceinline__ unsigned short f2bf(float f) {
    unsigned int u = __float_as_uint(f);
    u = (u + 0x7fffu + ((u >> 16) & 1u)) >> 16;
    return (unsigned short)u;
}
__device__ __forceinline__ float bfs(unsigned short h) { return __uint_as_float(((unsigned int)h) << 16); }
__device__ __forceinline__ float bflo(unsigned int u) { return __uint_as_float(u << 16); }
__device__ __forceinline__ float bfhi(unsigned int u) { return __uint_as_float(u & 0xffff0000u); }

// ---------------- fp32 -> bf16 bulk convert ----------------
__global__ void to_bf16_k(const float* __restrict__ in, unsigned short* __restrict__ out, int n4) {
    int i = blockIdx.x * blockDim.x + threadIdx.x;
    if (i >= n4) return;
    float4 v = ((const float4*)in)[i];
    ((ushort4*)out)[i] = make_ushort4(f2bf(v.x), f2bf(v.y), f2bf(v.z), f2bf(v.w));
}

// ---------------- degree count ----------------
__global__ void count_edges_k(const int* __restrict__ dst, int E, int* __restrict__ cnt) {
    int i = blockIdx.x * blockDim.x + threadIdx.x;
    int stride = gridDim.x * blockDim.x;
    for (int e = i; e < E; e += stride) atomicAdd(&cnt[dst[e]], 1);
}

// ---------------- hierarchical scan ----------------
__device__ __forceinline__ int wave_incl_scan(int v, int lane) {
#pragma unroll
    for (int d = 1; d < 64; d <<= 1) {
        int u = __shfl_up(v, d);
        if (lane >= d) v += u;
    }
    return v;
}

__global__ void block_sum_k(const int* __restrict__ cnt, int N, int* __restrict__ bsum) {
    const int t = threadIdx.x;
    const int base = blockIdx.x * SCAN_CHUNK;
    int s = 0;
    for (int i = t; i < SCAN_CHUNK; i += 256) {
        int idx = base + i;
        if (idx < N) s += cnt[idx];
    }
    const int lane = t & 63, wid = t >> 6;
#pragma unroll
    for (int d = 32; d; d >>= 1) s += __shfl_down(s, d);
    __shared__ int ws[4];
    if (lane == 0) ws[wid] = s;
    __syncthreads();
    if (t == 0) bsum[blockIdx.x] = ws[0] + ws[1] + ws[2] + ws[3];
}

__global__ void scan_bsums_k(int* __restrict__ bsum, int nb) {
    int lane = threadIdx.x;
    int v = (lane < nb) ? bsum[lane] : 0;
    int incl = wave_incl_scan(v, lane);
    if (lane < nb) bsum[lane] = incl - v;
}

__global__ void scan_write_k(const int* __restrict__ cnt, const int* __restrict__ bsum, int N,
                             int* __restrict__ off, int* __restrict__ cursor,
                             float* __restrict__ inv) {
    const int t = threadIdx.x;
    const int base = blockIdx.x * SCAN_CHUNK;
    const int idx0 = base + t * 16;
    int pre[16];
    int s = 0;
#pragma unroll
    for (int j = 0; j < 16; ++j) {
        int i = idx0 + j;
        int c = (i < N) ? cnt[i] : 0;
        pre[j] = s;
        s += c;
    }
    const int lane = t & 63, wid = t >> 6;
    int incl = wave_incl_scan(s, lane);
    __shared__ int ws[4];
    if (lane == 63) ws[wid] = incl;
    __syncthreads();
    if (t == 0) {
        int a = 0;
#pragma unroll
        for (int w = 0; w < 4; ++w) { int tmp = ws[w]; ws[w] = a; a += tmp; }
    }
    __syncthreads();
    const int tbase = bsum[blockIdx.x] + (incl - s) + ws[wid];
#pragma unroll
    for (int j = 0; j < 16; ++j) {
        int i = idx0 + j;
        if (i < N) {
            int c = cnt[i];
            int o = tbase + pre[j];
            off[i] = o;
            cursor[i] = o;
            inv[i] = 1.0f / fmaxf((float)c, 1.0f);
        }
    }
}

// ---------------- XCD-sliced CSR fill ----------------
// blocks with (blockIdx&7)==s handle only edges whose csr position lands in slice s,
// so each csr region is written by (mostly) one XCD and lines merge in its L2.
__global__ void csr_fill_sliced_k(const int* __restrict__ src, const int* __restrict__ dst,
                                  const int* __restrict__ off, int E,
                                  int* __restrict__ cursor, int* __restrict__ csr,
                                  float slice_scale) {
    const int slice = blockIdx.x & 7;
    const int g = blockIdx.x >> 3;
    const int ng = gridDim.x >> 3;
    int i = g * blockDim.x + threadIdx.x;
    int stride = ng * blockDim.x;
    for (int e = i; e < E; e += stride) {
        int d = dst[e];
        int o = off[d];
        int s = (int)((float)o * slice_scale);
        s = s > 7 ? 7 : s;
        if (s == slice) {
            int pos = atomicAdd(&cursor[d], 1);
            csr[pos] = src[e];
        }
    }
}

// ---------------- weight pre-pack into MFMA B-fragment order (bf16) ----------------
__global__ void wfrag_build_k(const float* __restrict__ Wl, const float* __restrict__ Wr,
                              int CIN, int KIT, unsigned short* __restrict__ wf) {
    int t = blockIdx.x * blockDim.x + threadIdx.x;
    int lane = t & 63;
    int q = t >> 6;
    if (q >= 8 * KIT) return;
    int kit = q % KIT;
    int ct = q / KIT;
    int col = ct * 16 + (lane & 15);
    bf16x8 v;
#pragma unroll
    for (int j = 0; j < 8; ++j) {
        int kg = kit * 32 + ((lane >> 4) << 3) + j;
        float f = (kg < CIN) ? Wl[(size_t)kg * 128 + col] : Wr[(size_t)(kg - CIN) * 128 + col];
        v[j] = (short)f2bf(f);
    }
    ((bf16x8*)wf)[q * 64 + lane] = v;
}

// ---------------- fused gather-mean + MFMA gemm ----------------
// out[32 rows x 128] = [mean_agg(feat) | xin] (bf16) @ [Wl;Wr] (bf16 frags) + bl.
// feat/xin are bf16 [N,CIN]. Gather goes straight into the swizzled LDS A-tile.
template<int CIN>
__launch_bounds__(256)
__global__ void fused_sage_k(const unsigned short* __restrict__ feat,
                             const unsigned short* __restrict__ xin,
                             const int* __restrict__ csr, const int* __restrict__ off,
                             const int* __restrict__ endp, const float* __restrict__ inv,
                             const unsigned short* __restrict__ wfrag,
                             const float* __restrict__ bl, float* __restrict__ out, int N) {
    constexpr int KT = 2 * CIN;
    constexpr int KIT = KT / 32;
    __shared__ unsigned short sA[32 * KT];   // [row][k] bf16, XOR-swizzled by (row&7)<<4 bytes

    const int t = threadIdx.x;
    const int lane = t & 63, wave = t >> 6;
    const int rowbase = blockIdx.x * 32;

    // ---- xin half: direct bf16 copy, 16B chunks
    constexpr int CH8 = CIN / 8;
    for (int i = t; i < 32 * CH8; i += 256) {
        int r = i / CH8, c8 = i % CH8;
        if (rowbase + r < N) {
            uint4 v = ((const uint4*)(xin + (size_t)(rowbase + r) * CIN))[c8];
            int byte = ((r * KT + CIN + c8 * 8) * 2) ^ ((r & 7) << 4);
            *(uint4*)((char*)sA + byte) = v;
        }
    }

    // ---- agg half: wave gathers 8 rows' neighbor means
#pragma unroll
    for (int rr = 0; rr < 8; ++rr) {
        int r = wave * 8 + rr;
        int n = rowbase + r;
        if (n < N) {
            int o = off[n], eend = endp[n];
            if constexpr (CIN == 128) {
                float a0 = 0.f, a1 = 0.f;
                int e = o;
                for (; e + 1 < eend; e += 2) {
                    unsigned int u0 = ((const unsigned int*)(feat + (size_t)csr[e] * 128))[lane];
                    unsigned int u1 = ((const unsigned int*)(feat + (size_t)csr[e + 1] * 128))[lane];
                    a0 += bflo(u0) + bflo(u1);
                    a1 += bfhi(u0) + bfhi(u1);
                }
                if (e < eend) {
                    unsigned int u = ((const unsigned int*)(feat + (size_t)csr[e] * 128))[lane];
                    a0 += bflo(u); a1 += bfhi(u);
                }
                float iv = inv[n];
                unsigned int pk = (unsigned int)f2bf(a0 * iv) | ((unsigned int)f2bf(a1 * iv) << 16);
                int byte = ((r * KT + 2 * lane) * 2) ^ ((r & 7) << 4);
                *(unsigned int*)((char*)sA + byte) = pk;
            } else {
                float a0 = 0.f;
                int e = o;
                for (; e + 1 < eend; e += 2) {
                    a0 += bfs(feat[(size_t)csr[e] * CIN + lane]);
                    a0 += bfs(feat[(size_t)csr[e + 1] * CIN + lane]);
                }
                if (e < eend) a0 += bfs(feat[(size_t)csr[e] * CIN + lane]);
                unsigned short pk = f2bf(a0 * inv[n]);
                int byte = ((r * KT + lane) * 2) ^ ((r & 7) << 4);
                *(unsigned short*)((char*)sA + byte) = pk;
            }
        }
    }
    __syncthreads();

    // ---- MFMA K-loop
    f32x4 acc00 = {0.f,0.f,0.f,0.f}, acc01 = acc00, acc10 = acc00, acc11 = acc00;
    const int koff = (lane >> 4) << 4;             // bytes
    const int swz = (lane & 7) << 4;
    const int base0 = (lane & 15) * KT * 2 + koff;
    const int base1 = (16 + (lane & 15)) * KT * 2 + koff;
    const bf16x8* wf8 = (const bf16x8*)wfrag;
    const int bq0 = (wave * 2 + 0) * KIT;
    const int bq1 = (wave * 2 + 1) * KIT;

#pragma unroll
    for (int kit = 0; kit < KIT; ++kit) {
        bf16x8 fa0 = *(const bf16x8*)((const char*)sA + ((base0 + kit * 64) ^ swz));
        bf16x8 fa1 = *(const bf16x8*)((const char*)sA + ((base1 + kit * 64) ^ swz));
        bf16x8 fb0 = wf8[(bq0 + kit) * 64 + lane];
        bf16x8 fb1 = wf8[(bq1 + kit) * 64 + lane];
        acc00 = __builtin_amdgcn_mfma_f32_16x16x32_bf16(fa0, fb0, acc00, 0, 0, 0);
        acc01 = __builtin_amdgcn_mfma_f32_16x16x32_bf16(fa0, fb1, acc01, 0, 0, 0);
        acc10 = __builtin_amdgcn_mfma_f32_16x16x32_bf16(fa1, fb0, acc10, 0, 0, 0);
        acc11 = __builtin_amdgcn_mfma_f32_16x16x32_bf16(fa1, fb1, acc11, 0, 0, 0);
    }

    // epilogue: C/D layout col=lane&15, row=(lane>>4)*4+reg
    const int c0 = wave * 32 + (lane & 15);
    const int c1 = c0 + 16;
    const float b0 = bl[c0], b1 = bl[c1];
#pragma unroll
    for (int r = 0; r < 4; ++r) {
        int row0 = rowbase + ((lane >> 4) << 2) + r;
        int row1 = row0 + 16;
        if (row0 < N) {
            out[(size_t)row0 * 128 + c0] = acc00[r] + b0;
            out[(size_t)row0 * 128 + c1] = acc01[r] + b1;
        }
        if (row1 < N) {
            out[(size_t)row1 * 128 + c0] = acc10[r] + b0;
            out[(size_t)row1 * 128 + c1] = acc11[r] + b1;
        }
    }
}

// ---------------- BN stats ----------------
__global__ void bn_stats_k(const float* __restrict__ h, int N, float* __restrict__ stats) {
    const int col = threadIdx.x & 127;
    const int part = threadIdx.x >> 7;
    float s = 0.f, s2 = 0.f;
    for (int r = blockIdx.x * 2 + part; r < N; r += gridDim.x * 2) {
        float v = h[(size_t)r * 128 + col];
        s += v;
        s2 += v * v;
    }
    __shared__ float red[2][256];
    red[0][threadIdx.x] = s;
    red[1][threadIdx.x] = s2;
    __syncthreads();
    if (threadIdx.x < 128) {
        atomicAdd(&stats[col], red[0][threadIdx.x] + red[0][threadIdx.x + 128]);
        atomicAdd(&stats[128 + col], red[1][threadIdx.x] + red[1][threadIdx.x + 128]);
    }
}

__global__ void bn_finalize_k(const float* __restrict__ g, const float* __restrict__ be,
                              float* __restrict__ stats, int N) {
    int c = threadIdx.x;
    if (c < 128) {
        float mu = stats[c] / (float)N;
        float var = stats[128 + c] / (float)N - mu * mu;
        float sc = g[c] * rsqrtf(var + BN_EPS);
        stats[256 + c] = sc;
        stats[384 + c] = be[c] - mu * sc;
    }
}

// BN apply + ReLU, bf16 output
__global__ void bn_apply_bf16_k(const float* __restrict__ h, const float* __restrict__ stats,
                                unsigned short* __restrict__ hb, int total4) {
    int i = blockIdx.x * blockDim.x + threadIdx.x;
    int stride = gridDim.x * blockDim.x;
    const float* sc = stats + 256;
    const float* sh = stats + 384;
    for (; i < total4; i += stride) {
        int c0 = (i & 31) * 4;
        float4 v = ((const float4*)h)[i];
        float r0 = fmaxf(v.x * sc[c0 + 0] + sh[c0 + 0], 0.f);
        float r1 = fmaxf(v.y * sc[c0 + 1] + sh[c0 + 1], 0.f);
        float r2 = fmaxf(v.z * sc[c0 + 2] + sh[c0 + 2], 0.f);
        float r3 = fmaxf(v.w * sc[c0 + 3] + sh[c0 + 3], 0.f);
        ((ushort4*)hb)[i] = make_ushort4(f2bf(r0), f2bf(r1), f2bf(r2), f2bf(r3));
    }
}

// BN apply + ReLU + bf16 out + p = relu(bn(h)).Wl2  (wave-per-node)
__global__ void bn_apply_p_k(const float* __restrict__ h, const float* __restrict__ stats,
                             unsigned short* __restrict__ hb, const float* __restrict__ Wl2,
                             float* __restrict__ p, int N) {
    const int lane = threadIdx.x & 63;
    const int n = (int)((blockIdx.x * (long long)blockDim.x + threadIdx.x) >> 6);
    if (n >= N) return;
    const float2 sc = ((const float2*)(stats + 256))[lane];
    const float2 sh = ((const float2*)(stats + 384))[lane];
    const float2 w  = ((const float2*)Wl2)[lane];
    float2 v = ((const float2*)(h + (size_t)n * 128))[lane];
    v.x = fmaxf(v.x * sc.x + sh.x, 0.f);
    v.y = fmaxf(v.y * sc.y + sh.y, 0.f);
    unsigned int pk = (unsigned int)f2bf(v.x) | ((unsigned int)f2bf(v.y) << 16);
    ((unsigned int*)(hb + (size_t)n * 128))[lane] = pk;
    float s = v.x * w.x + v.y * w.y;
#pragma unroll
    for (int o = 32; o; o >>= 1) s += __shfl_down(s, o);
    if (lane == 0) p[n] = s;
}

// ---------------- layer 2 final ----------------
__global__ void layer2_final_k(const unsigned short* __restrict__ hb, const float* __restrict__ p,
                               const int* __restrict__ csr, const int* __restrict__ off,
                               const int* __restrict__ endp, const float* __restrict__ inv,
                               const float* __restrict__ Wr2, const float* __restrict__ bl2,
                               const float* __restrict__ wF, const float* __restrict__ bF,
                               float* __restrict__ out, int N) {
    const int lane = threadIdx.x & 63;
    const int n = (int)((blockIdx.x * (long long)blockDim.x + threadIdx.x) >> 6);
    if (n >= N) return;
    float2 w = ((const float2*)Wr2)[lane];
    unsigned int u = ((const unsigned int*)(hb + (size_t)n * 128))[lane];
    float dotp = bflo(u) * w.x + bfhi(u) * w.y;
    float ps = 0.f;
    const int o = off[n], e_end = endp[n];
    for (int e = o + lane; e < e_end; e += 64) ps += p[csr[e]];
    float s = dotp + ps * inv[n];
#pragma unroll
    for (int ow = 32; ow; ow >>= 1) s += __shfl_down(s, ow);
    if (lane == 0) {
        float z = (s + bl2[0]) * wF[0] + bF[0];
        out[n] = 1.f / (1.f + expf(-z));
    }
}

extern "C" void kernel_launch(void* const* d_in, const int* in_sizes, int n_in,
                              void* d_out, int out_size, void* d_ws, size_t ws_size,
                              hipStream_t stream) {
    const float* x   = (const float*)d_in[0];
    const int*   ei  = (const int*)d_in[1];
    const int E = in_sizes[1] / 2;
    const int N = in_sizes[0] / 64;
    const int* src = ei;
    const int* dst = ei + E;
    const float* Wl0 = (const float*)d_in[2];
    const float* bl0 = (const float*)d_in[3];
    const float* Wr0 = (const float*)d_in[4];
    const float* Wl1 = (const float*)d_in[5];
    const float* bl1 = (const float*)d_in[6];
    const float* Wr1 = (const float*)d_in[7];
    const float* Wl2 = (const float*)d_in[8];
    const float* bl2 = (const float*)d_in[9];
    const float* Wr2 = (const float*)d_in[10];
    const float* g0  = (const float*)d_in[11];
    const float* be0 = (const float*)d_in[12];
    const float* g1  = (const float*)d_in[13];
    const float* be1 = (const float*)d_in[14];
    const float* wF  = (const float*)d_in[15];
    const float* bF  = (const float*)d_in[16];

    float*          B   = (float*)d_ws;                       // h fp32   [N,128]
    unsigned short* Bb  = (unsigned short*)(B + (size_t)N * 128);   // h bf16 [N,128]
    unsigned short* xb  = Bb + (size_t)N * 128;                // x bf16  [N,64]
    int*   cnt   = (int*)(xb + (size_t)N * 64);  // [N]  (reused as p later)
    int*   off   = cnt + N;                      // [N]
    int*   cursor= off + N;                      // [N] (= row end after fill)
    float* inv   = (float*)(cursor + N);         // [N]
    int*   csr   = (int*)(inv + N);              // [E]
    float* stats = (float*)(csr + E);            // [512]
    int*   bsum  = (int*)(stats + 512);          // [64]
    unsigned short* wf0 = (unsigned short*)(bsum + 64);      // 16K bf16
    unsigned short* wf1 = wf0 + 8 * 4 * 64 * 8;              // 32K bf16
    float* p     = (float*)cnt;                  // [N] alias, valid after scan_write
    float* out = (float*)d_out;

    const int gemm_grid = (N + 31) / 32;
    const int wave_grid = (N + 3) / 4;
    const int nb = (N + SCAN_CHUNK - 1) / SCAN_CHUNK;

    // ---- weight pre-pack + x -> bf16 (independent of graph work)
    wfrag_build_k<<<(8 * 4 * 64 + 255) / 256, 256, 0, stream>>>(Wl0, Wr0, 64, 4, wf0);
    wfrag_build_k<<<(8 * 8 * 64 + 255) / 256, 256, 0, stream>>>(Wl1, Wr1, 128, 8, wf1);
    to_bf16_k<<<(N * 16 + 255) / 256, 256, 0, stream>>>(x, xb, N * 16);

    // ---- CSR build
    hipMemsetAsync(cnt, 0, (size_t)N * sizeof(int), stream);
    count_edges_k<<<2048, 256, 0, stream>>>(dst, E, cnt);
    block_sum_k<<<nb, 256, 0, stream>>>(cnt, N, bsum);
    scan_bsums_k<<<1, 64, 0, stream>>>(bsum, nb);
    scan_write_k<<<nb, 256, 0, stream>>>(cnt, bsum, N, off, cursor, inv);
    csr_fill_sliced_k<<<2048, 256, 0, stream>>>(src, dst, off, E, cursor, csr, 8.0f / (float)E);

    // ---- layer 0: xb[N,64] -> B[N,128] (fused gather+gemm)
    fused_sage_k<64><<<gemm_grid, 256, 0, stream>>>(xb, xb, csr, off, cursor, inv, wf0, bl0, B, N);
    hipMemsetAsync(stats, 0, 256 * sizeof(float), stream);
    bn_stats_k<<<512, 256, 0, stream>>>(B, N, stats);
    bn_finalize_k<<<1, 128, 0, stream>>>(g0, be0, stats, N);
    bn_apply_bf16_k<<<2048, 256, 0, stream>>>(B, stats, Bb, N * 32);

    // ---- layer 1: Bb[N,128] -> B[N,128] (fused gather+gemm)
    fused_sage_k<128><<<gemm_grid, 256, 0, stream>>>(Bb, Bb, csr, off, cursor, inv, wf1, bl1, B, N);
    hipMemsetAsync(stats, 0, 256 * sizeof(float), stream);
    bn_stats_k<<<512, 256, 0, stream>>>(B, N, stats);
    bn_finalize_k<<<1, 128, 0, stream>>>(g1, be1, stats, N);
    // fused BN apply + ReLU + bf16 write + p = h.Wl2
    bn_apply_p_k<<<wave_grid, 256, 0, stream>>>(B, stats, Bb, Wl2, p, N);

    // ---- layer 2 via scalar trick
    layer2_final_k<<<wave_grid, 256, 0, stream>>>(Bb, p, csr, off, cursor, inv,
                                                  Wr2, bl2, wF, bF, out, N);
}